// Round 4
// baseline (497.406 us; speedup 1.0000x reference)
//
#include <hip/hip_runtime.h>

#define BATCH 8
#define DIN   512
#define SEQ   8192
#define ECH   1024   // concatenated conv output channels (fore 512 | back 512)
#define HCH   256    // per-direction hidden channels
#define CL    32     // scan chunk length
#define NCHNK (SEQ / CL)   // 256 chunks per row
#define NSC   16           // superchunks (16 chunks each)

typedef __bf16 bf16;
typedef __bf16 bf16x8 __attribute__((ext_vector_type(8)));
typedef float  floatx4 __attribute__((ext_vector_type(4)));

__device__ __forceinline__ void async_ld16(void* lds, const void* g) {
  __builtin_amdgcn_global_load_lds(
      (const __attribute__((address_space(1))) unsigned int*)g,
      (__attribute__((address_space(3))) unsigned int*)lds, 16, 0, 0);
}

__device__ __forceinline__ float bits2f(unsigned u) {
  return __builtin_bit_cast(float, u);
}

// minGRU step: a = sigmoid(-g), bt = sigmoid(g) * (h>=0 ? 1+h : exp(h))
__device__ __forceinline__ void gru_ab(unsigned v, float& a, float& bt) {
  float hh = bits2f(v << 16);
  float g  = bits2f(v & 0xffff0000u);
  float eg = __expf(-g);
  float sg = 1.f / (1.f + eg);   // sigmoid(g)
  a = eg * sg;                    // sigmoid(-g)
  float gv = hh >= 0.f ? 1.f + hh : __expf(hh);
  bt = sg * gv;
}

// ---------------------------------------------------------------------------
// Kernel 1: convert/permute weights to bf16 in MFMA-FRAGMENT-MAJOR order:
// for 16x16x32 B-fragments, element (n,d) lives at
//   Wf[ ((n>>4)*16 + (d>>5))*512 + (((d>>3)&3)*16 + (n&15))*8 + (d&7) ]
// so one wave's fragment load (lane = quad*16+l15) is a single contiguous
// 1 KB global_load_dwordx4 -> B never needs LDS staging.
// ---------------------------------------------------------------------------
__global__ void k_wconv(const float* __restrict__ wf, const float* __restrict__ bfo,
                        const float* __restrict__ wb, const float* __restrict__ bb,
                        bf16* __restrict__ Wf, float* __restrict__ bias) {
  int idx = blockIdx.x * 256 + threadIdx.x;
  if (idx < ECH * DIN) {
    int n = idx >> 9, d = idx & 511;
    int dir = n >> 9, r = n & 511, e = r >> 1, isg = r & 1;
    int s = e + (isg ? HCH : 0);
    const float* w = dir ? wb : wf;
    size_t o = ((size_t)((n >> 4) * 16 + (d >> 5)) << 9) +
               ((((d >> 3) & 3) * 16 + (n & 15)) << 3) + (d & 7);
    Wf[o] = (bf16)w[s * DIN + d];
  }
  if (idx < ECH) {
    int dir = idx >> 9, r = idx & 511, e = r >> 1, isg = r & 1;
    int s = e + (isg ? HCH : 0);
    bias[idx] = (dir ? bb : bfo)[s];
  }
}

// ---------------------------------------------------------------------------
// Kernel 2: tiled transpose + convert  x[b,d,l] fp32 -> xT[b,l,d] bf16
// ---------------------------------------------------------------------------
__global__ void k_xpose(const float* __restrict__ x, bf16* __restrict__ xT) {
  __shared__ float T[64 * 65];
  int t = threadIdx.x;
  int l0 = blockIdx.x * 64;
  int d0 = blockIdx.y * 64;
  int b  = blockIdx.z;
  const float* xb = x + (size_t)b * DIN * SEQ;
#pragma unroll
  for (int p = 0; p < 4; ++p) {
    int dl = (t >> 4) + p * 16;
    int l4 = (t & 15) * 4;
    float4 v = *(const float4*)(xb + (size_t)(d0 + dl) * SEQ + l0 + l4);
    T[dl * 65 + l4 + 0] = v.x;
    T[dl * 65 + l4 + 1] = v.y;
    T[dl * 65 + l4 + 2] = v.z;
    T[dl * 65 + l4 + 3] = v.w;
  }
  __syncthreads();
  bf16* xTb = xT + (size_t)b * SEQ * DIN;
#pragma unroll
  for (int p = 0; p < 2; ++p) {
    int ll = (t >> 3) + p * 32;
    int d8 = (t & 7) * 8;
    bf16x8 h;
#pragma unroll
    for (int j = 0; j < 8; ++j) h[j] = (bf16)T[(d8 + j) * 65 + ll];
    *(bf16x8*)(xTb + (size_t)(l0 + ll) * DIN + d0 + d8) = h;
  }
}

// ---------------------------------------------------------------------------
// Kernel 3: bf16 MFMA GEMM  hg[b,l,n] = sum_d xT[b,l,d] * Wf[frag(n,d)] + bias[n]
// 128x128 tile, 4 waves (2x2), BK=64, 16x16x32 frags.
// ROUND-0 VERIFIED SKELETON (single A buffer, two full __syncthreads drains
// per K-tile, identical staging addressing, identical epilogue) with exactly
// ONE delta: B is NOT staged in LDS -- it is loaded per K-tile from the
// fragment-major Wf as 8 coalesced 1KB wave-loads (L2-resident, 1 MB total).
// LDS traffic per K-tile halves (4 DMA writes + 8 ds_read_b128 per wave,
// was 8 + 16).
// Fused epilogue: bias+pack to Cs[128][132], hg store, per-chunk minGRU
// affine composition (A,B) straight from Cs.
// ---------------------------------------------------------------------------
#define BKK 64
#define NKT (DIN / BKK)     // 8 K-tiles

__launch_bounds__(256, 4)
__global__ void k_gemm(const bf16* __restrict__ xT, const bf16* __restrict__ Wf,
                       const float* __restrict__ bias, bf16* __restrict__ hg,
                       float* __restrict__ Asum, float* __restrict__ Bsum) {
  // staging: As[128][64] (8192 elems); epilogue: Cs[128][132] overlay
  __shared__ __align__(16) bf16 lds[16896];
  bf16* As = lds;

  int t = threadIdx.x;
  int lane = t & 63, wave = t >> 6;
  int l15 = lane & 15, quad = lane >> 4, rsw = l15 & 7;
  int wm = wave >> 1, wn = wave & 1;
  int mb = wm * 64, nb = wn * 64;

  // XCD-locality remap (round-0): all 8 n-tiles of one l-tile on one XCD.
  int lin = blockIdx.x + 8 * blockIdx.y;   // 0..511
  int xcd = lin & 7;
  int seq = lin >> 3;                      // 0..63
  int ltile = xcd + 8 * (seq >> 3);        // 0..63
  int ntile = seq & 7;
  int n0 = ntile * 128;
  int l0 = ltile * 128;
  int b  = blockIdx.z;

  const bf16* gA = xT + ((size_t)b * SEQ + l0) * DIN;
  int nb16 = (n0 >> 4) + wn * 4;           // this wave's base 16-row B block

  float bb4[4];
#pragma unroll
  for (int ni = 0; ni < 4; ++ni) bb4[ni] = bias[n0 + nb + ni * 16 + l15];

  int srow = wave * 32 + (lane >> 3);
  int scol = ((lane & 7) ^ ((lane >> 3) & 7)) * 8;   // XOR-preswizzled src col

  floatx4 acc[4][4];
#pragma unroll
  for (int i = 0; i < 4; ++i)
#pragma unroll
    for (int j = 0; j < 4; ++j) acc[i][j] = (floatx4){0.f, 0.f, 0.f, 0.f};

#pragma unroll
  for (int kt = 0; kt < NKT; ++kt) {
    int k0 = kt * BKK;
    // stage A(kt): 4 global_load_lds per thread, linear LDS dest
    // (wave-uniform base + lane*16B), XOR-preswizzled global source col.
#pragma unroll
    for (int q = 0; q < 4; ++q)
      async_ld16(As + (wave * 32 + q * 8) * 64,
                 gA + (size_t)(srow + q * 8) * DIN + k0 + scol);

    // B fragments for this K-tile: 8 coalesced 1KB wave-loads from L2.
    // Issued before the drain so their latency overlaps it.
    bf16x8 bfr[4][2];
#pragma unroll
    for (int i = 0; i < 4; ++i)
#pragma unroll
      for (int k2 = 0; k2 < 2; ++k2)
        bfr[i][k2] = *(const bf16x8*)(Wf +
            (((size_t)(nb16 + i) * 16 + kt * 2 + k2) << 9) + lane * 8);

    __syncthreads();   // full drain: all waves' A(kt) visible in LDS

#pragma unroll
    for (int k2 = 0; k2 < 2; ++k2) {
      bf16x8 af[4];
#pragma unroll
      for (int i = 0; i < 4; ++i)
        af[i] = *(const bf16x8*)(As + (mb + i * 16 + l15) * 64 +
                                 (((k2 * 4 + quad) ^ rsw) * 8));
#pragma unroll
      for (int mi = 0; mi < 4; ++mi)
#pragma unroll
        for (int ni = 0; ni < 4; ++ni)
          acc[mi][ni] = __builtin_amdgcn_mfma_f32_16x16x32_bf16(
              af[mi], bfr[ni][k2], acc[mi][ni], 0, 0, 0);
    }
    __syncthreads();   // all reads done before next tile's overwrite
  }

  // epilogue: bias add, pack to bf16 in LDS (stride 132 breaks conflicts), store
  bf16* Cs = lds;  // [128][132]
#pragma unroll
  for (int mi = 0; mi < 4; ++mi)
#pragma unroll
    for (int ni = 0; ni < 4; ++ni)
#pragma unroll
      for (int r = 0; r < 4; ++r) {
        int row = mb + mi * 16 + quad * 4 + r;
        int col = nb + ni * 16 + l15;
        Cs[row * 132 + col] = (bf16)(acc[mi][ni][r] + bb4[ni]);
      }
  __syncthreads();
  bf16* hgb = hg + ((size_t)b * SEQ + l0) * ECH + n0;
#pragma unroll
  for (int p = 0; p < 8; ++p) {
    int row = p * 16 + (t >> 4);
    int seg = t & 15;
    *(bf16x8*)(hgb + (size_t)row * ECH + seg * 8) =
        *(const bf16x8*)(Cs + row * 132 + seg * 8);
  }

  // fused per-chunk minGRU composition
  // wave = chunk within tile (4 chunks of 32), lane = e-pair within tile (64)
  {
    int dirn = ntile >> 2;               // n0 >> 9
    int c = wave, el = lane;
    float A = 1.f, Bc = 0.f;
#pragma unroll 8
    for (int i = 0; i < CL; ++i) {
      int row = c * CL + (dirn ? (CL - 1 - i) : i);
      unsigned v = *(const unsigned*)(Cs + row * 132 + 2 * el);
      float a, bt;
      gru_ab(v, a, bt);
      A *= a;
      Bc = a * Bc + bt;
    }
    int chunkg = ltile * 4 + c;
    int eg = ((n0 & 511) >> 1) + el;
    size_t o = ((size_t)(b * 2 + dirn) * NCHNK + chunkg) * 256 + eg;
    Asum[o] = A;
    Bsum[o] = Bc;
  }
}

// ---------------------------------------------------------------------------
// Kernel 4: full inter-chunk scan in ONE kernel (replaces scan2a/2b/2c).
// 16 blocks (row2 = b*2+dir) x 256 threads (e). Sequential over 256 chunks;
// loads are independent of the carry chain so the compiler prefetches ahead.
// Writes hin[c] = carry-in for every chunk. Provably identical math to the
// old 3-kernel chain (same composition order per direction).
// ---------------------------------------------------------------------------
__global__ void k_scan2(const float* __restrict__ Asum, const float* __restrict__ Bsum,
                        float* __restrict__ hin) {
  int e = threadIdx.x, row2 = blockIdx.x, dir = row2 & 1;
  size_t base = (size_t)row2 * NCHNK;
  float h = 0.f;
#pragma unroll 8
  for (int i = 0; i < NCHNK; ++i) {
    int c = dir ? (NCHNK - 1 - i) : i;
    size_t o = (base + c) * 256 + e;
    hin[o] = h;
    h = Asum[o] * h + Bsum[o];
  }
}

// ---------------------------------------------------------------------------
// Kernel 5: recompute local scan with carry-in, transpose via LDS (stride 33),
// write out[b, dir*256+e, l] as coalesced float4.
// ---------------------------------------------------------------------------
__global__ void k_scan3(const bf16* __restrict__ hg, const float* __restrict__ hin,
                        float* __restrict__ out) {
  __shared__ float T[256 * 33];
  int t = threadIdx.x;
  int chunk = blockIdx.x, dir = blockIdx.y, b = blockIdx.z;
  const bf16* hb = hg + (size_t)b * SEQ * ECH + dir * 512 + 2 * t;
  float h = hin[((size_t)(b * 2 + dir) * NCHNK + chunk) * 256 + t];
  int lbase = chunk * CL;
#pragma unroll 8
  for (int i = 0; i < CL; ++i) {
    int ll = dir ? (CL - 1 - i) : i;
    unsigned v = *(const unsigned*)(hb + (size_t)(lbase + ll) * ECH);
    float a, bt;
    gru_ab(v, a, bt);
    h = a * h + bt;
    T[t * 33 + ll] = h;
  }
  __syncthreads();
  float* ob = out + ((size_t)b * 512 + dir * 256) * SEQ + lbase;
#pragma unroll
  for (int p = 0; p < 8; ++p) {
    int row = p * 32 + (t >> 3);   // e channel
    int c4 = (t & 7) * 4;          // l within chunk
    float4 v4;
    v4.x = T[row * 33 + c4 + 0];
    v4.y = T[row * 33 + c4 + 1];
    v4.z = T[row * 33 + c4 + 2];
    v4.w = T[row * 33 + c4 + 3];
    *(float4*)(ob + (size_t)row * SEQ + c4) = v4;
  }
}

// ---------------------------------------------------------------------------
extern "C" void kernel_launch(void* const* d_in, const int* in_sizes, int n_in,
                              void* d_out, int out_size, void* d_ws, size_t ws_size,
                              hipStream_t stream) {
  const float* x   = (const float*)d_in[0];
  const float* wf  = (const float*)d_in[1];
  const float* bfo = (const float*)d_in[2];
  const float* wb  = (const float*)d_in[3];
  const float* bb  = (const float*)d_in[4];
  float* out = (float*)d_out;
  char* ws = (char*)d_ws;

  // workspace layout (bytes):
  bf16*  xT   = (bf16*)(ws);                       // 67,108,864
  bf16*  hg   = (bf16*)(ws + 67108864);            // 134,217,728
  bf16*  Wfm  = (bf16*)(ws + 201326592);           // 1,048,576
  float* bias = (float*)(ws + 202375168);          // 4,096
  float* Asum = (float*)(ws + 202379264);          // 4,194,304
  float* Bsum = (float*)(ws + 206573568);          // 4,194,304
  float* hin  = (float*)(ws + 210767872);          // 4,194,304  (total ~214.9 MB)

  k_wconv<<<2048, 256, 0, stream>>>(wf, bfo, wb, bb, Wfm, bias);
  k_xpose<<<dim3(SEQ / 64, DIN / 64, BATCH), 256, 0, stream>>>(x, xT);
  k_gemm<<<dim3(ECH / 128, SEQ / 128, BATCH), 256, 0, stream>>>(xT, Wfm, bias, hg,
                                                                Asum, Bsum);
  k_scan2<<<16, 256, 0, stream>>>(Asum, Bsum, hin);
  k_scan3<<<dim3(NCHNK, 2, BATCH), 256, 0, stream>>>(hg, hin, out);
}

// Round 5
// 382.934 us; speedup vs baseline: 1.2989x; 1.2989x over previous
//
#include <hip/hip_runtime.h>

#define BATCH 8
#define DIN   512
#define SEQ   8192
#define ECH   1024   // concatenated conv output channels (fore 512 | back 512)
#define HCH   256    // per-direction hidden channels
#define CL    32     // scan chunk length
#define NCHNK (SEQ / CL)   // 256 chunks per row
#define NSC   16           // superchunks (16 chunks each)

typedef __bf16 bf16;
typedef __bf16 bf16x8 __attribute__((ext_vector_type(8)));
typedef float  floatx4 __attribute__((ext_vector_type(4)));

__device__ __forceinline__ void async_ld16(void* lds, const void* g) {
  __builtin_amdgcn_global_load_lds(
      (const __attribute__((address_space(1))) unsigned int*)g,
      (__attribute__((address_space(3))) unsigned int*)lds, 16, 0, 0);
}

__device__ __forceinline__ float bits2f(unsigned u) {
  return __builtin_bit_cast(float, u);
}

// minGRU step: a = sigmoid(-g), bt = sigmoid(g) * (h>=0 ? 1+h : exp(h))
__device__ __forceinline__ void gru_ab(unsigned v, float& a, float& bt) {
  float hh = bits2f(v << 16);
  float g  = bits2f(v & 0xffff0000u);
  float eg = __expf(-g);
  float sg = 1.f / (1.f + eg);   // sigmoid(g)
  a = eg * sg;                    // sigmoid(-g)
  float gv = hh >= 0.f ? 1.f + hh : __expf(hh);
  bt = sg * gv;
}

// ---------------------------------------------------------------------------
// Kernel 1: convert/permute weights to bf16 in MFMA-FRAGMENT-MAJOR order:
// for 16x16x32 B-fragments, element (n,d) lives at
//   Wf[ ((n>>4)*16 + (d>>5))*512 + (((d>>3)&3)*16 + (n&15))*8 + (d&7) ]
// so one wave's fragment load (lane = quad*16+l15) is a single contiguous
// 1 KB global_load_dwordx4 -> B never needs LDS staging. (Verified round 4.)
// ---------------------------------------------------------------------------
__global__ void k_wconv(const float* __restrict__ wf, const float* __restrict__ bfo,
                        const float* __restrict__ wb, const float* __restrict__ bb,
                        bf16* __restrict__ Wf, float* __restrict__ bias) {
  int idx = blockIdx.x * 256 + threadIdx.x;
  if (idx < ECH * DIN) {
    int n = idx >> 9, d = idx & 511;
    int dir = n >> 9, r = n & 511, e = r >> 1, isg = r & 1;
    int s = e + (isg ? HCH : 0);
    const float* w = dir ? wb : wf;
    size_t o = ((size_t)((n >> 4) * 16 + (d >> 5)) << 9) +
               ((((d >> 3) & 3) * 16 + (n & 15)) << 3) + (d & 7);
    Wf[o] = (bf16)w[s * DIN + d];
  }
  if (idx < ECH) {
    int dir = idx >> 9, r = idx & 511, e = r >> 1, isg = r & 1;
    int s = e + (isg ? HCH : 0);
    bias[idx] = (dir ? bb : bfo)[s];
  }
}

// ---------------------------------------------------------------------------
// Kernel 2: tiled transpose + convert  x[b,d,l] fp32 -> xT[b,l,d] bf16
// ---------------------------------------------------------------------------
__global__ void k_xpose(const float* __restrict__ x, bf16* __restrict__ xT) {
  __shared__ float T[64 * 65];
  int t = threadIdx.x;
  int l0 = blockIdx.x * 64;
  int d0 = blockIdx.y * 64;
  int b  = blockIdx.z;
  const float* xb = x + (size_t)b * DIN * SEQ;
#pragma unroll
  for (int p = 0; p < 4; ++p) {
    int dl = (t >> 4) + p * 16;
    int l4 = (t & 15) * 4;
    float4 v = *(const float4*)(xb + (size_t)(d0 + dl) * SEQ + l0 + l4);
    T[dl * 65 + l4 + 0] = v.x;
    T[dl * 65 + l4 + 1] = v.y;
    T[dl * 65 + l4 + 2] = v.z;
    T[dl * 65 + l4 + 3] = v.w;
  }
  __syncthreads();
  bf16* xTb = xT + (size_t)b * SEQ * DIN;
#pragma unroll
  for (int p = 0; p < 2; ++p) {
    int ll = (t >> 3) + p * 32;
    int d8 = (t & 7) * 8;
    bf16x8 h;
#pragma unroll
    for (int j = 0; j < 8; ++j) h[j] = (bf16)T[(d8 + j) * 65 + ll];
    *(bf16x8*)(xTb + (size_t)(l0 + ll) * DIN + d0 + d8) = h;
  }
}

// ---------------------------------------------------------------------------
// Kernel 3: bf16 MFMA GEMM  hg[b,l,n] = sum_d xT[b,l,d] * Wf[frag(n,d)] + bias[n]
// 128x128 tile, 4 waves (2x2), BK=64, 16x16x32 frags.
// Round-4 passing kernel with ONE change: __launch_bounds__(256,3).
// Round 4's (256,4) capped unified regs at 128/wave; acc takes 64 (AGPR side)
// leaving 64 arch VGPRs, but bfr[4][2]+af+addressing needs ~80 -> per-K-tile
// scratch spills (FETCH 43->220 MB, WRITE 139->468 MB, dur 106->208 us).
// (256,3) = 170 unified regs -> 106 arch after acc: fits, no spill,
// 3 blocks/CU (12 waves/CU, same occupancy regime as round 0).
// ---------------------------------------------------------------------------
#define BKK 64
#define NKT (DIN / BKK)     // 8 K-tiles

__launch_bounds__(256, 3)
__global__ void k_gemm(const bf16* __restrict__ xT, const bf16* __restrict__ Wf,
                       const float* __restrict__ bias, bf16* __restrict__ hg,
                       float* __restrict__ Asum, float* __restrict__ Bsum) {
  // staging: As[128][64] (8192 elems); epilogue: Cs[128][132] overlay
  __shared__ __align__(16) bf16 lds[16896];
  bf16* As = lds;

  int t = threadIdx.x;
  int lane = t & 63, wave = t >> 6;
  int l15 = lane & 15, quad = lane >> 4, rsw = l15 & 7;
  int wm = wave >> 1, wn = wave & 1;
  int mb = wm * 64, nb = wn * 64;

  // XCD-locality remap (round-0): all 8 n-tiles of one l-tile on one XCD.
  int lin = blockIdx.x + 8 * blockIdx.y;   // 0..511
  int xcd = lin & 7;
  int seq = lin >> 3;                      // 0..63
  int ltile = xcd + 8 * (seq >> 3);        // 0..63
  int ntile = seq & 7;
  int n0 = ntile * 128;
  int l0 = ltile * 128;
  int b  = blockIdx.z;

  const bf16* gA = xT + ((size_t)b * SEQ + l0) * DIN;
  int nb16 = (n0 >> 4) + wn * 4;           // this wave's base 16-row B block

  float bb4[4];
#pragma unroll
  for (int ni = 0; ni < 4; ++ni) bb4[ni] = bias[n0 + nb + ni * 16 + l15];

  int srow = wave * 32 + (lane >> 3);
  int scol = ((lane & 7) ^ ((lane >> 3) & 7)) * 8;   // XOR-preswizzled src col

  floatx4 acc[4][4];
#pragma unroll
  for (int i = 0; i < 4; ++i)
#pragma unroll
    for (int j = 0; j < 4; ++j) acc[i][j] = (floatx4){0.f, 0.f, 0.f, 0.f};

#pragma unroll
  for (int kt = 0; kt < NKT; ++kt) {
    int k0 = kt * BKK;
    // stage A(kt): 4 global_load_lds per thread, linear LDS dest
    // (wave-uniform base + lane*16B), XOR-preswizzled global source col.
#pragma unroll
    for (int q = 0; q < 4; ++q)
      async_ld16(As + (wave * 32 + q * 8) * 64,
                 gA + (size_t)(srow + q * 8) * DIN + k0 + scol);

    // B fragments for this K-tile: 8 coalesced 1KB wave-loads from L2.
    // Issued before the drain so their latency overlaps it.
    bf16x8 bfr[4][2];
#pragma unroll
    for (int i = 0; i < 4; ++i)
#pragma unroll
      for (int k2 = 0; k2 < 2; ++k2)
        bfr[i][k2] = *(const bf16x8*)(Wf +
            (((size_t)(nb16 + i) * 16 + kt * 2 + k2) << 9) + lane * 8);

    __syncthreads();   // full drain: all waves' A(kt) visible in LDS

#pragma unroll
    for (int k2 = 0; k2 < 2; ++k2) {
      bf16x8 af[4];
#pragma unroll
      for (int i = 0; i < 4; ++i)
        af[i] = *(const bf16x8*)(As + (mb + i * 16 + l15) * 64 +
                                 (((k2 * 4 + quad) ^ rsw) * 8));
#pragma unroll
      for (int mi = 0; mi < 4; ++mi)
#pragma unroll
        for (int ni = 0; ni < 4; ++ni)
          acc[mi][ni] = __builtin_amdgcn_mfma_f32_16x16x32_bf16(
              af[mi], bfr[ni][k2], acc[mi][ni], 0, 0, 0);
    }
    __syncthreads();   // all reads done before next tile's overwrite
  }

  // epilogue: bias add, pack to bf16 in LDS (stride 132 breaks conflicts), store
  bf16* Cs = lds;  // [128][132]
#pragma unroll
  for (int mi = 0; mi < 4; ++mi)
#pragma unroll
    for (int ni = 0; ni < 4; ++ni)
#pragma unroll
      for (int r = 0; r < 4; ++r) {
        int row = mb + mi * 16 + quad * 4 + r;
        int col = nb + ni * 16 + l15;
        Cs[row * 132 + col] = (bf16)(acc[mi][ni][r] + bb4[ni]);
      }
  __syncthreads();
  bf16* hgb = hg + ((size_t)b * SEQ + l0) * ECH + n0;
#pragma unroll
  for (int p = 0; p < 8; ++p) {
    int row = p * 16 + (t >> 4);
    int seg = t & 15;
    *(bf16x8*)(hgb + (size_t)row * ECH + seg * 8) =
        *(const bf16x8*)(Cs + row * 132 + seg * 8);
  }

  // fused per-chunk minGRU composition
  // wave = chunk within tile (4 chunks of 32), lane = e-pair within tile (64)
  {
    int dirn = ntile >> 2;               // n0 >> 9
    int c = wave, el = lane;
    float A = 1.f, Bc = 0.f;
#pragma unroll 8
    for (int i = 0; i < CL; ++i) {
      int row = c * CL + (dirn ? (CL - 1 - i) : i);
      unsigned v = *(const unsigned*)(Cs + row * 132 + 2 * el);
      float a, bt;
      gru_ab(v, a, bt);
      A *= a;
      Bc = a * Bc + bt;
    }
    int chunkg = ltile * 4 + c;
    int eg = ((n0 & 511) >> 1) + el;
    size_t o = ((size_t)(b * 2 + dirn) * NCHNK + chunkg) * 256 + eg;
    Asum[o] = A;
    Bsum[o] = Bc;
  }
}

// ---------------------------------------------------------------------------
// Kernel 4: full inter-chunk scan in ONE kernel (replaces scan2a/2b/2c).
// 16 blocks (row2 = b*2+dir) x 256 threads (e). Sequential over 256 chunks;
// loads are independent of the carry chain so the compiler prefetches ahead.
// Writes hin[c] = carry-in for every chunk. (Verified round 4.)
// ---------------------------------------------------------------------------
__global__ void k_scan2(const float* __restrict__ Asum, const float* __restrict__ Bsum,
                        float* __restrict__ hin) {
  int e = threadIdx.x, row2 = blockIdx.x, dir = row2 & 1;
  size_t base = (size_t)row2 * NCHNK;
  float h = 0.f;
#pragma unroll 8
  for (int i = 0; i < NCHNK; ++i) {
    int c = dir ? (NCHNK - 1 - i) : i;
    size_t o = (base + c) * 256 + e;
    hin[o] = h;
    h = Asum[o] * h + Bsum[o];
  }
}

// ---------------------------------------------------------------------------
// Kernel 5: recompute local scan with carry-in, transpose via LDS (stride 33),
// write out[b, dir*256+e, l] as coalesced float4.
// ---------------------------------------------------------------------------
__global__ void k_scan3(const bf16* __restrict__ hg, const float* __restrict__ hin,
                        float* __restrict__ out) {
  __shared__ float T[256 * 33];
  int t = threadIdx.x;
  int chunk = blockIdx.x, dir = blockIdx.y, b = blockIdx.z;
  const bf16* hb = hg + (size_t)b * SEQ * ECH + dir * 512 + 2 * t;
  float h = hin[((size_t)(b * 2 + dir) * NCHNK + chunk) * 256 + t];
  int lbase = chunk * CL;
#pragma unroll 8
  for (int i = 0; i < CL; ++i) {
    int ll = dir ? (CL - 1 - i) : i;
    unsigned v = *(const unsigned*)(hb + (size_t)(lbase + ll) * ECH);
    float a, bt;
    gru_ab(v, a, bt);
    h = a * h + bt;
    T[t * 33 + ll] = h;
  }
  __syncthreads();
  float* ob = out + ((size_t)b * 512 + dir * 256) * SEQ + lbase;
#pragma unroll
  for (int p = 0; p < 8; ++p) {
    int row = p * 32 + (t >> 3);   // e channel
    int c4 = (t & 7) * 4;          // l within chunk
    float4 v4;
    v4.x = T[row * 33 + c4 + 0];
    v4.y = T[row * 33 + c4 + 1];
    v4.z = T[row * 33 + c4 + 2];
    v4.w = T[row * 33 + c4 + 3];
    *(float4*)(ob + (size_t)row * SEQ + c4) = v4;
  }
}

// ---------------------------------------------------------------------------
extern "C" void kernel_launch(void* const* d_in, const int* in_sizes, int n_in,
                              void* d_out, int out_size, void* d_ws, size_t ws_size,
                              hipStream_t stream) {
  const float* x   = (const float*)d_in[0];
  const float* wf  = (const float*)d_in[1];
  const float* bfo = (const float*)d_in[2];
  const float* wb  = (const float*)d_in[3];
  const float* bb  = (const float*)d_in[4];
  float* out = (float*)d_out;
  char* ws = (char*)d_ws;

  // workspace layout (bytes):
  bf16*  xT   = (bf16*)(ws);                       // 67,108,864
  bf16*  hg   = (bf16*)(ws + 67108864);            // 134,217,728
  bf16*  Wfm  = (bf16*)(ws + 201326592);           // 1,048,576
  float* bias = (float*)(ws + 202375168);          // 4,096
  float* Asum = (float*)(ws + 202379264);          // 4,194,304
  float* Bsum = (float*)(ws + 206573568);          // 4,194,304
  float* hin  = (float*)(ws + 210767872);          // 4,194,304  (total ~214.9 MB)

  k_wconv<<<2048, 256, 0, stream>>>(wf, bfo, wb, bb, Wfm, bias);
  k_xpose<<<dim3(SEQ / 64, DIN / 64, BATCH), 256, 0, stream>>>(x, xT);
  k_gemm<<<dim3(ECH / 128, SEQ / 128, BATCH), 256, 0, stream>>>(xT, Wfm, bias, hg,
                                                                Asum, Bsum);
  k_scan2<<<16, 256, 0, stream>>>(Asum, Bsum, hin);
  k_scan3<<<dim3(NCHNK, 2, BATCH), 256, 0, stream>>>(hg, hin, out);
}